// Round 8
// baseline (93.415 us; speedup 1.0000x reference)
//
#include <hip/hip_runtime.h>
#include <math.h>

#define BB 4
#define S 8192
#define C 256
#define NW 2048
#define WS 256
#define PSZ 256
#define DD 32
#define KK 65
#define TOTW (BB * NW) /* 8192 */

#define KC 64
#define LDA 68  /* 64 + 4 pad, keeps 16B alignment (68*4=272=17*16) */
#define NBKT 64                 /* position buckets per batch (128 rows each) */
#define TBKT (BB * NBKT)        /* 256 total buckets */

// ---------------------------------------------------------------------------
// Kernel 0: pack B [256 k][512 cols] = [ Wp^T | Wa ]; block 0 zeroes the
// bucket counters (stream-ordered before the histogram).
// ---------------------------------------------------------------------------
__global__ __launch_bounds__(256) void prep_B(const float* __restrict__ Wp,
                                              const float* __restrict__ Wa,
                                              float* __restrict__ Bp,
                                              int* __restrict__ cnt) {
    const int k = blockIdx.x;
    const int t = threadIdx.x;
    Bp[k * 512 + t] = Wp[t * WS + k];
    Bp[k * 512 + 256 + t] = Wa[k * C + t];
    if (k == 0) cnt[t] = 0;
}

// ---------------------------------------------------------------------------
// Kernel 1: f32 blocked GEMM  C[8192 x 512] = ct[8192 x 256] @ B[256 x 512].
// bn 4..7 -> g. bn 0..3 (h cols): fused p_t partial reduction (no h buffer).
// ---------------------------------------------------------------------------
__global__ __launch_bounds__(256, 4) void precomp_gemm(const float* __restrict__ ct,
                                                       const float* __restrict__ Bp,
                                                       const float* __restrict__ Vp,
                                                       float* __restrict__ ptpart,
                                                       float* __restrict__ g) {
    __shared__ __align__(16) float Al[KC][LDA];
    __shared__ __align__(16) float Bl[KC][LDA];

    const int t = threadIdx.x;
    const int bm = blockIdx.x >> 3;       // 0..127
    const int bn = blockIdx.x & 7;        // 0..7
    const int tm = t >> 4;                // 0..15
    const int tn = t & 15;                // 0..15
    const int sm = t >> 2;                // 0..63
    const int sf = t & 3;                 // 0..3

    const float4* ct4 = (const float4*)ct;   // [8192][64]
    const float4* B4  = (const float4*)Bp;   // [256][128]

    float acc[4][4] = {{0.f}};

    for (int kc = 0; kc < 256; kc += KC) {
        __syncthreads();
#pragma unroll
        for (int i = 0; i < 4; i++) {
            const float4 a = ct4[(size_t)(bm * 64 + sm) * 64 + (kc >> 2) + sf + i * 4];
            const int kl = (sf + i * 4) * 4;
            Al[kl + 0][sm] = a.x;
            Al[kl + 1][sm] = a.y;
            Al[kl + 2][sm] = a.z;
            Al[kl + 3][sm] = a.w;
        }
#pragma unroll
        for (int i = 0; i < 4; i++) {
            const float4 b = B4[(size_t)(kc + sm) * 128 + bn * 16 + sf + i * 4];
            *(float4*)&Bl[sm][(sf + i * 4) * 4] = b;
        }
        __syncthreads();

#pragma unroll 8
        for (int kk = 0; kk < KC; kk++) {
            const float4 a = *(const float4*)&Al[kk][tm * 4];
            const float4 b = *(const float4*)&Bl[kk][tn * 4];
            acc[0][0] = fmaf(a.x, b.x, acc[0][0]);
            acc[0][1] = fmaf(a.x, b.y, acc[0][1]);
            acc[0][2] = fmaf(a.x, b.z, acc[0][2]);
            acc[0][3] = fmaf(a.x, b.w, acc[0][3]);
            acc[1][0] = fmaf(a.y, b.x, acc[1][0]);
            acc[1][1] = fmaf(a.y, b.y, acc[1][1]);
            acc[1][2] = fmaf(a.y, b.z, acc[1][2]);
            acc[1][3] = fmaf(a.y, b.w, acc[1][3]);
            acc[2][0] = fmaf(a.z, b.x, acc[2][0]);
            acc[2][1] = fmaf(a.z, b.y, acc[2][1]);
            acc[2][2] = fmaf(a.z, b.z, acc[2][2]);
            acc[2][3] = fmaf(a.z, b.w, acc[2][3]);
            acc[3][0] = fmaf(a.w, b.x, acc[3][0]);
            acc[3][1] = fmaf(a.w, b.y, acc[3][1]);
            acc[3][2] = fmaf(a.w, b.z, acc[3][2]);
            acc[3][3] = fmaf(a.w, b.w, acc[3][3]);
        }
    }

    if (bn >= 4) {
        const int col = bn * 64 + tn * 4 - 256;
#pragma unroll
        for (int i = 0; i < 4; i++) {
            const int row = bm * 64 + tm * 4 + i;
            *(float4*)&g[(size_t)row * 256 + col] =
                make_float4(acc[i][0], acc[i][1], acc[i][2], acc[i][3]);
        }
    } else {
        const float4 vp4 = ((const float4*)Vp)[bn * 16 + tn];
#pragma unroll
        for (int i = 0; i < 4; i++) {
            float v = tanhf(acc[i][0]) * vp4.x;
            v = fmaf(tanhf(acc[i][1]), vp4.y, v);
            v = fmaf(tanhf(acc[i][2]), vp4.z, v);
            v = fmaf(tanhf(acc[i][3]), vp4.w, v);
#pragma unroll
            for (int off = 8; off >= 1; off >>= 1) v += __shfl_xor(v, off);
            if (tn == 0) {
                const int row = bm * 64 + tm * 4 + i;
                ptpart[row * 4 + bn] = v;
            }
        }
    }
}

// ---------------------------------------------------------------------------
// Kernel 2: finalize p_t + position histogram.
// ---------------------------------------------------------------------------
__global__ __launch_bounds__(256) void pt_hist(const float* __restrict__ ptpart,
                                               float* __restrict__ pt,
                                               int* __restrict__ cnt) {
    const int wg = blockIdx.x * 256 + threadIdx.x;
    const float4 pp = ((const float4*)ptpart)[wg];
    const float x = (pp.x + pp.y) + (pp.z + pp.w);
    const float p = (float)S / (1.f + expf(-x));
    pt[wg] = p;
    const int s0 = (int)p;
    const int bkt = (wg >> 11) * NBKT + min(NBKT - 1, max(0, s0 >> 7));
    atomicAdd(&cnt[bkt], 1);
}

// ---------------------------------------------------------------------------
// Kernel 3: exclusive scan of 256 bucket counts -> scatter cursors.
// ---------------------------------------------------------------------------
__global__ __launch_bounds__(256) void scan_kernel(const int* __restrict__ cnt,
                                                   int* __restrict__ offs) {
    __shared__ int sh[TBKT];
    const int t = threadIdx.x;
    const int v = cnt[t];
    sh[t] = v;
    __syncthreads();
    for (int d = 1; d < TBKT; d <<= 1) {
        const int x = (t >= d) ? sh[t - d] : 0;
        __syncthreads();
        sh[t] += x;
        __syncthreads();
    }
    offs[t] = sh[t] - v;   // exclusive
}

// ---------------------------------------------------------------------------
// Kernel 4: scatter window ids into position-sorted permutation.
// ---------------------------------------------------------------------------
__global__ __launch_bounds__(256) void scatter_kernel(const float* __restrict__ pt,
                                                      int* __restrict__ offs,
                                                      int* __restrict__ perm) {
    const int wg = blockIdx.x * 256 + threadIdx.x;
    const int s0 = (int)pt[wg];
    const int bkt = (wg >> 11) * NBKT + min(NBKT - 1, max(0, s0 >> 7));
    const int pos = atomicAdd(&offs[bkt], 1);
    perm[pos] = wg;
}

// ---------------------------------------------------------------------------
// Kernel 5: gather-attention v4. R7 lesson: online softmax serialized
// {4 dependent shuffles + 3 exps + rescale} into EVERY iteration (latency-
// bound, VALUBusy 34%). v4 = two-pass, all iterations independent:
//   P1: all 17 scores -> e[17] (68 shuffle chains, pipelined)
//   P2: one max-reduce (M), e=exp(e-M), den=sum+2 shuffles; fold gauss into e
//       (den uses PRE-gauss exp, matching reference softmax*gauss)
//   P3: reload q rows (L1-hot) + pure a += e[it]*q  (no rescale/exp/shuffle)
//   P4: add-merge across groups (shared M -> no rescale), divide, store.
// e[17] fully unrolled -> registers (runtime-indexed arrays spill, rule #20).
// ---------------------------------------------------------------------------
__global__ __launch_bounds__(256) void attn(const float* __restrict__ q,
                                            const float* __restrict__ g,
                                            const float* __restrict__ pt,
                                            const int* __restrict__ perm,
                                            float* __restrict__ out) {
    const int tid = threadIdx.x;
    const int lane = tid & 63;
    const int wv = tid >> 6;
    const int bid = blockIdx.x;
    const int sb = (bid & 7) * 256 + (bid >> 3);   // XCD-chunked sorted order
    const int wg = perm[sb * 4 + wv];
    const int b = wg >> 11;                    // NW = 2048
    const int grp = lane >> 4;                 // key sub-slot
    const int sub = lane & 15;                 // channel group

    const float p = pt[wg];
    const int s0 = (int)p;                     // trunc == floor (p > 0)

    const float* grow = g + (size_t)wg * C + sub * 4;
    const float4 g0 = *(const float4*)(grow);
    const float4 g1 = *(const float4*)(grow + 64);
    const float4 g2 = *(const float4*)(grow + 128);
    const float4 g3 = *(const float4*)(grow + 192);

    const float* qb = q + (size_t)b * S * C + sub * 4;

    // ---- Phase 1: all scores (independent chains) ----
    float e[17];
#pragma unroll
    for (int it = 0; it < 17; it++) {
        const int k = it * 4 + grp;
        const int s = s0 + k - DD;
        const bool valid = (k <= 64) && ((unsigned)s < (unsigned)S);
        const float* qr = qb + (size_t)min(max(s, 0), S - 1) * C;
        const float4 q0 = *(const float4*)(qr);
        const float4 q1 = *(const float4*)(qr + 64);
        const float4 q2 = *(const float4*)(qr + 128);
        const float4 q3 = *(const float4*)(qr + 192);

        float d0 = q0.x * g0.x, d1 = q1.x * g1.x, d2 = q2.x * g2.x, d3 = q3.x * g3.x;
        d0 = fmaf(q0.y, g0.y, d0); d1 = fmaf(q1.y, g1.y, d1);
        d2 = fmaf(q2.y, g2.y, d2); d3 = fmaf(q3.y, g3.y, d3);
        d0 = fmaf(q0.z, g0.z, d0); d1 = fmaf(q1.z, g1.z, d1);
        d2 = fmaf(q2.z, g2.z, d2); d3 = fmaf(q3.z, g3.z, d3);
        d0 = fmaf(q0.w, g0.w, d0); d1 = fmaf(q1.w, g1.w, d1);
        d2 = fmaf(q2.w, g2.w, d2); d3 = fmaf(q3.w, g3.w, d3);
        float d = (d0 + d1) + (d2 + d3);
#pragma unroll
        for (int off = 8; off >= 1; off >>= 1) d += __shfl_xor(d, off);
        e[it] = valid ? d : -3e38f;
    }

    // ---- Phase 2: window max, den, fold gauss ----
    float m = e[0];
#pragma unroll
    for (int it = 1; it < 17; it++) m = fmaxf(m, e[it]);
    float M = fmaxf(m, __shfl_xor(m, 16));
    M = fmaxf(M, __shfl_xor(M, 32));

    float den = 0.f;
#pragma unroll
    for (int it = 0; it < 17; it++) {
        e[it] = __expf(e[it] - M);
        den += e[it];
    }
    den += __shfl_xor(den, 16);
    den += __shfl_xor(den, 32);

#pragma unroll
    for (int it = 0; it < 17; it++) {
        const int s = s0 + it * 4 + grp - DD;
        const float fs = (float)s - p;
        const float tt = fs * (1.f / (float)DD);
        e[it] *= __expf(-2.f * tt * tt);
    }

    // ---- Phase 3: pure accumulation (reload q rows, L1-hot) ----
    float4 a0 = {0, 0, 0, 0}, a1 = {0, 0, 0, 0}, a2 = {0, 0, 0, 0}, a3 = {0, 0, 0, 0};
#pragma unroll
    for (int it = 0; it < 17; it++) {
        const int s = s0 + it * 4 + grp - DD;
        const float* qr = qb + (size_t)min(max(s, 0), S - 1) * C;
        const float4 q0 = *(const float4*)(qr);
        const float4 q1 = *(const float4*)(qr + 64);
        const float4 q2 = *(const float4*)(qr + 128);
        const float4 q3 = *(const float4*)(qr + 192);
        const float w = e[it];
        a0.x = fmaf(w, q0.x, a0.x); a0.y = fmaf(w, q0.y, a0.y);
        a0.z = fmaf(w, q0.z, a0.z); a0.w = fmaf(w, q0.w, a0.w);
        a1.x = fmaf(w, q1.x, a1.x); a1.y = fmaf(w, q1.y, a1.y);
        a1.z = fmaf(w, q1.z, a1.z); a1.w = fmaf(w, q1.w, a1.w);
        a2.x = fmaf(w, q2.x, a2.x); a2.y = fmaf(w, q2.y, a2.y);
        a2.z = fmaf(w, q2.z, a2.z); a2.w = fmaf(w, q2.w, a2.w);
        a3.x = fmaf(w, q3.x, a3.x); a3.y = fmaf(w, q3.y, a3.y);
        a3.z = fmaf(w, q3.z, a3.z); a3.w = fmaf(w, q3.w, a3.w);
    }

    // ---- Phase 4: merge groups (shared M -> plain adds), divide, store ----
#define MERGE(v) { v += __shfl_xor(v, 16); v += __shfl_xor(v, 32); }
    MERGE(a0.x) MERGE(a0.y) MERGE(a0.z) MERGE(a0.w)
    MERGE(a1.x) MERGE(a1.y) MERGE(a1.z) MERGE(a1.w)
    MERGE(a2.x) MERGE(a2.y) MERGE(a2.z) MERGE(a2.w)
    MERGE(a3.x) MERGE(a3.y) MERGE(a3.z) MERGE(a3.w)
#undef MERGE

    float4 o = a0;
    if (grp == 1) o = a1;
    else if (grp == 2) o = a2;
    else if (grp == 3) o = a3;

    const float r = 1.f / den;
    o.x *= r; o.y *= r; o.z *= r; o.w *= r;

    *(float4*)(out + (size_t)wg * C + lane * 4) = o;
}

// ---------------------------------------------------------------------------
extern "C" void kernel_launch(void* const* d_in, const int* in_sizes, int n_in,
                              void* d_out, int out_size, void* d_ws, size_t ws_size,
                              hipStream_t stream) {
    const float* q  = (const float*)d_in[0];
    const float* ct = (const float*)d_in[1];
    const float* Wa = (const float*)d_in[2];
    const float* Wp = (const float*)d_in[3];
    const float* Vp = (const float*)d_in[4];
    float* out = (float*)d_out;

    char* ws = (char*)d_ws;
    float* Bp     = (float*)ws;                   // 512 KB
    float* ptpart = (float*)(ws + 524288);        // 128 KB
    float* pt     = (float*)(ws + 655360);        // 32 KB
    int*   cnt    = (int*)  (ws + 688128);        // 1 KB
    int*   offs   = (int*)  (ws + 689152);        // 1 KB
    int*   perm   = (int*)  (ws + 690176);        // 32 KB
    float* g      = (float*)(ws + 722944);        // 8 MB

    prep_B<<<256, 256, 0, stream>>>(Wp, Wa, Bp, cnt);
    precomp_gemm<<<1024, 256, 0, stream>>>(ct, Bp, Vp, ptpart, g);
    pt_hist<<<TOTW / 256, 256, 0, stream>>>(ptpart, pt, cnt);
    scan_kernel<<<1, TBKT, 0, stream>>>(cnt, offs);
    scatter_kernel<<<TOTW / 256, 256, 0, stream>>>(pt, offs, perm);
    attn<<<TOTW / 4, 256, 0, stream>>>(q, g, pt, perm, out);
}

// Round 9
// 88.655 us; speedup vs baseline: 1.0537x; 1.0537x over previous
//
#include <hip/hip_runtime.h>
#include <math.h>

#define BB 4
#define S 8192
#define C 256
#define NW 2048
#define WS 256
#define PSZ 256
#define DD 32
#define KK 65
#define TOTW (BB * NW) /* 8192 */

#define KC 64
#define LDA 68
#define NBKT 64
#define TBKT (BB * NBKT)

// ---------------------------------------------------------------------------
// Kernel 0: pack B [256 k][512 cols] = [ Wp^T | Wa ]; zero bucket counters.
// ---------------------------------------------------------------------------
__global__ __launch_bounds__(256) void prep_B(const float* __restrict__ Wp,
                                              const float* __restrict__ Wa,
                                              float* __restrict__ Bp,
                                              int* __restrict__ cnt) {
    const int k = blockIdx.x;
    const int t = threadIdx.x;
    Bp[k * 512 + t] = Wp[t * WS + k];
    Bp[k * 512 + 256 + t] = Wa[k * C + t];
    if (k == 0) cnt[t] = 0;
}

// ---------------------------------------------------------------------------
// Kernel 1: f32 blocked GEMM  C[8192 x 512] = ct[8192 x 256] @ B[256 x 512].
// bn 4..7 -> g. bn 0..3 (h cols): fused p_t partial reduction (no h buffer).
// ---------------------------------------------------------------------------
__global__ __launch_bounds__(256, 4) void precomp_gemm(const float* __restrict__ ct,
                                                       const float* __restrict__ Bp,
                                                       const float* __restrict__ Vp,
                                                       float* __restrict__ ptpart,
                                                       float* __restrict__ g) {
    __shared__ __align__(16) float Al[KC][LDA];
    __shared__ __align__(16) float Bl[KC][LDA];

    const int t = threadIdx.x;
    const int bm = blockIdx.x >> 3;
    const int bn = blockIdx.x & 7;
    const int tm = t >> 4;
    const int tn = t & 15;
    const int sm = t >> 2;
    const int sf = t & 3;

    const float4* ct4 = (const float4*)ct;
    const float4* B4  = (const float4*)Bp;

    float acc[4][4] = {{0.f}};

    for (int kc = 0; kc < 256; kc += KC) {
        __syncthreads();
#pragma unroll
        for (int i = 0; i < 4; i++) {
            const float4 a = ct4[(size_t)(bm * 64 + sm) * 64 + (kc >> 2) + sf + i * 4];
            const int kl = (sf + i * 4) * 4;
            Al[kl + 0][sm] = a.x;
            Al[kl + 1][sm] = a.y;
            Al[kl + 2][sm] = a.z;
            Al[kl + 3][sm] = a.w;
        }
#pragma unroll
        for (int i = 0; i < 4; i++) {
            const float4 b = B4[(size_t)(kc + sm) * 128 + bn * 16 + sf + i * 4];
            *(float4*)&Bl[sm][(sf + i * 4) * 4] = b;
        }
        __syncthreads();

#pragma unroll 8
        for (int kk = 0; kk < KC; kk++) {
            const float4 a = *(const float4*)&Al[kk][tm * 4];
            const float4 b = *(const float4*)&Bl[kk][tn * 4];
            acc[0][0] = fmaf(a.x, b.x, acc[0][0]);
            acc[0][1] = fmaf(a.x, b.y, acc[0][1]);
            acc[0][2] = fmaf(a.x, b.z, acc[0][2]);
            acc[0][3] = fmaf(a.x, b.w, acc[0][3]);
            acc[1][0] = fmaf(a.y, b.x, acc[1][0]);
            acc[1][1] = fmaf(a.y, b.y, acc[1][1]);
            acc[1][2] = fmaf(a.y, b.z, acc[1][2]);
            acc[1][3] = fmaf(a.y, b.w, acc[1][3]);
            acc[2][0] = fmaf(a.z, b.x, acc[2][0]);
            acc[2][1] = fmaf(a.z, b.y, acc[2][1]);
            acc[2][2] = fmaf(a.z, b.z, acc[2][2]);
            acc[2][3] = fmaf(a.z, b.w, acc[2][3]);
            acc[3][0] = fmaf(a.w, b.x, acc[3][0]);
            acc[3][1] = fmaf(a.w, b.y, acc[3][1]);
            acc[3][2] = fmaf(a.w, b.z, acc[3][2]);
            acc[3][3] = fmaf(a.w, b.w, acc[3][3]);
        }
    }

    if (bn >= 4) {
        const int col = bn * 64 + tn * 4 - 256;
#pragma unroll
        for (int i = 0; i < 4; i++) {
            const int row = bm * 64 + tm * 4 + i;
            *(float4*)&g[(size_t)row * 256 + col] =
                make_float4(acc[i][0], acc[i][1], acc[i][2], acc[i][3]);
        }
    } else {
        const float4 vp4 = ((const float4*)Vp)[bn * 16 + tn];
#pragma unroll
        for (int i = 0; i < 4; i++) {
            float v = tanhf(acc[i][0]) * vp4.x;
            v = fmaf(tanhf(acc[i][1]), vp4.y, v);
            v = fmaf(tanhf(acc[i][2]), vp4.z, v);
            v = fmaf(tanhf(acc[i][3]), vp4.w, v);
#pragma unroll
            for (int off = 8; off >= 1; off >>= 1) v += __shfl_xor(v, off);
            if (tn == 0) {
                const int row = bm * 64 + tm * 4 + i;
                ptpart[row * 4 + bn] = v;
            }
        }
    }
}

// ---------------------------------------------------------------------------
// Kernel 2: finalize p_t + position histogram.
// ---------------------------------------------------------------------------
__global__ __launch_bounds__(256) void pt_hist(const float* __restrict__ ptpart,
                                               float* __restrict__ pt,
                                               int* __restrict__ cnt) {
    const int wg = blockIdx.x * 256 + threadIdx.x;
    const float4 pp = ((const float4*)ptpart)[wg];
    const float x = (pp.x + pp.y) + (pp.z + pp.w);
    const float p = (float)S / (1.f + expf(-x));
    pt[wg] = p;
    const int s0 = (int)p;
    const int bkt = (wg >> 11) * NBKT + min(NBKT - 1, max(0, s0 >> 7));
    atomicAdd(&cnt[bkt], 1);
}

// ---------------------------------------------------------------------------
// Kernel 3: exclusive scan of 256 bucket counts.
// ---------------------------------------------------------------------------
__global__ __launch_bounds__(256) void scan_kernel(const int* __restrict__ cnt,
                                                   int* __restrict__ offs) {
    __shared__ int sh[TBKT];
    const int t = threadIdx.x;
    const int v = cnt[t];
    sh[t] = v;
    __syncthreads();
    for (int d = 1; d < TBKT; d <<= 1) {
        const int x = (t >= d) ? sh[t - d] : 0;
        __syncthreads();
        sh[t] += x;
        __syncthreads();
    }
    offs[t] = sh[t] - v;
}

// ---------------------------------------------------------------------------
// Kernel 4: scatter window ids into position-sorted permutation.
// ---------------------------------------------------------------------------
__global__ __launch_bounds__(256) void scatter_kernel(const float* __restrict__ pt,
                                                      int* __restrict__ offs,
                                                      int* __restrict__ perm) {
    const int wg = blockIdx.x * 256 + threadIdx.x;
    const int s0 = (int)pt[wg];
    const int bkt = (wg >> 11) * NBKT + min(NBKT - 1, max(0, s0 >> 7));
    const int pos = atomicAdd(&offs[bkt], 1);
    perm[pos] = wg;
}

// ---------------------------------------------------------------------------
// Kernel 5: gather-attention v5 — ONE WINDOW PER BLOCK, 4 waves cooperate.
// R8 lesson: 17 serial iters/wave can't pipeline at 64 VGPR (272 regs of
// loads needed). v5: kslot = tid>>4 (16 slots), key k = it*16+kslot -> only
// 5 iters; q rows held in regs (5x4 float4 = 80 VGPR) -> all loads issue
// up-front (full MLP), NO phase-3 reload (halves L2 gather traffic).
// Wave-local softmax (shuffles only), single __syncthreads, cross-wave
// merge with exp(m_w - M) rescale via 4KB LDS. Every kslot always has >=1
// valid key (valid-k range len >= 33 covers all residues mod 16).
// ---------------------------------------------------------------------------
__global__ __launch_bounds__(256, 3) void attn(const float* __restrict__ q,
                                               const float* __restrict__ g,
                                               const float* __restrict__ pt,
                                               const int* __restrict__ perm,
                                               float* __restrict__ out) {
    __shared__ __align__(16) float4 accbuf[4][64];
    __shared__ float mbuf[4], dbuf[4];

    const int tid = threadIdx.x;
    const int l = tid & 63;
    const int wv = tid >> 6;
    const int gw = l >> 4;                 // group within wave
    const int sub = l & 15;                // channel sub-slot
    const int kslot = tid >> 4;            // 0..15

    const int bid = blockIdx.x;
    const int sb = (bid & 7) * 1024 + (bid >> 3);   // XCD-chunked sorted order
    const int wg = perm[sb];
    const int b = wg >> 11;

    const float p = pt[wg];
    const int s0 = (int)p;

    const float* grow = g + (size_t)wg * C + sub * 4;
    const float4 g0 = *(const float4*)(grow);
    const float4 g1 = *(const float4*)(grow + 64);
    const float4 g2 = *(const float4*)(grow + 128);
    const float4 g3 = *(const float4*)(grow + 192);

    const float* qb = q + (size_t)b * S * C + sub * 4;

    // ---- load all 5 q rows for this kslot into registers (full MLP) ----
    float4 qh[5][4];
#pragma unroll
    for (int it = 0; it < 5; it++) {
        const int s = s0 + it * 16 + kslot - DD;
        const float* qr = qb + (size_t)min(max(s, 0), S - 1) * C;
        qh[it][0] = *(const float4*)(qr);
        qh[it][1] = *(const float4*)(qr + 64);
        qh[it][2] = *(const float4*)(qr + 128);
        qh[it][3] = *(const float4*)(qr + 192);
    }

    // ---- scores ----
    float e[5];
#pragma unroll
    for (int it = 0; it < 5; it++) {
        const int k = it * 16 + kslot;
        const int s = s0 + k - DD;
        const bool valid = (k <= 64) && ((unsigned)s < (unsigned)S);
        float d0 = qh[it][0].x * g0.x, d1 = qh[it][1].x * g1.x;
        float d2 = qh[it][2].x * g2.x, d3 = qh[it][3].x * g3.x;
        d0 = fmaf(qh[it][0].y, g0.y, d0); d1 = fmaf(qh[it][1].y, g1.y, d1);
        d2 = fmaf(qh[it][2].y, g2.y, d2); d3 = fmaf(qh[it][3].y, g3.y, d3);
        d0 = fmaf(qh[it][0].z, g0.z, d0); d1 = fmaf(qh[it][1].z, g1.z, d1);
        d2 = fmaf(qh[it][2].z, g2.z, d2); d3 = fmaf(qh[it][3].z, g3.z, d3);
        d0 = fmaf(qh[it][0].w, g0.w, d0); d1 = fmaf(qh[it][1].w, g1.w, d1);
        d2 = fmaf(qh[it][2].w, g2.w, d2); d3 = fmaf(qh[it][3].w, g3.w, d3);
        float d = (d0 + d1) + (d2 + d3);
#pragma unroll
        for (int off = 8; off >= 1; off >>= 1) d += __shfl_xor(d, off);
        e[it] = valid ? d : -3e38f;
    }

    // ---- wave-local softmax ----
    float m = e[0];
#pragma unroll
    for (int it = 1; it < 5; it++) m = fmaxf(m, e[it]);
    m = fmaxf(m, __shfl_xor(m, 16));
    m = fmaxf(m, __shfl_xor(m, 32));       // M_w: uniform across wave

    float den = 0.f;
#pragma unroll
    for (int it = 0; it < 5; it++) {
        e[it] = __expf(e[it] - m);
        den += e[it];
    }
    den += __shfl_xor(den, 16);
    den += __shfl_xor(den, 32);            // den_w (pre-gauss, per reference)

    // fold gaussian into weights
#pragma unroll
    for (int it = 0; it < 5; it++) {
        const float fs = (float)(s0 + it * 16 + kslot - DD) - p;
        const float tt = fs * (1.f / (float)DD);
        e[it] *= __expf(-2.f * tt * tt);
    }

    // ---- weighted accumulation from registers ----
    float4 a0 = {0,0,0,0}, a1 = {0,0,0,0}, a2 = {0,0,0,0}, a3 = {0,0,0,0};
#pragma unroll
    for (int it = 0; it < 5; it++) {
        const float w = e[it];
        a0.x = fmaf(w, qh[it][0].x, a0.x); a0.y = fmaf(w, qh[it][0].y, a0.y);
        a0.z = fmaf(w, qh[it][0].z, a0.z); a0.w = fmaf(w, qh[it][0].w, a0.w);
        a1.x = fmaf(w, qh[it][1].x, a1.x); a1.y = fmaf(w, qh[it][1].y, a1.y);
        a1.z = fmaf(w, qh[it][1].z, a1.z); a1.w = fmaf(w, qh[it][1].w, a1.w);
        a2.x = fmaf(w, qh[it][2].x, a2.x); a2.y = fmaf(w, qh[it][2].y, a2.y);
        a2.z = fmaf(w, qh[it][2].z, a2.z); a2.w = fmaf(w, qh[it][2].w, a2.w);
        a3.x = fmaf(w, qh[it][3].x, a3.x); a3.y = fmaf(w, qh[it][3].y, a3.y);
        a3.z = fmaf(w, qh[it][3].z, a3.z); a3.w = fmaf(w, qh[it][3].w, a3.w);
    }

    // ---- merge the wave's 4 kslots (shared M_w -> plain adds) ----
#define MERGE(v) { v += __shfl_xor(v, 16); v += __shfl_xor(v, 32); }
    MERGE(a0.x) MERGE(a0.y) MERGE(a0.z) MERGE(a0.w)
    MERGE(a1.x) MERGE(a1.y) MERGE(a1.z) MERGE(a1.w)
    MERGE(a2.x) MERGE(a2.y) MERGE(a2.z) MERGE(a2.w)
    MERGE(a3.x) MERGE(a3.y) MERGE(a3.z) MERGE(a3.w)
#undef MERGE

    float4 o = a0;
    if (gw == 1) o = a1;
    else if (gw == 2) o = a2;
    else if (gw == 3) o = a3;
    // lane l holds wave-partial for channel-f4 index f = l
    accbuf[wv][l] = o;
    if (l == 0) { mbuf[wv] = m; dbuf[wv] = den; }
    __syncthreads();

    // ---- cross-wave merge with rescale; wave 0 writes the row ----
    if (tid < 64) {
        const float M = fmaxf(fmaxf(mbuf[0], mbuf[1]), fmaxf(mbuf[2], mbuf[3]));
        const float sc0 = __expf(mbuf[0] - M);
        const float sc1 = __expf(mbuf[1] - M);
        const float sc2 = __expf(mbuf[2] - M);
        const float sc3 = __expf(mbuf[3] - M);
        const float dtot = dbuf[0]*sc0 + dbuf[1]*sc1 + dbuf[2]*sc2 + dbuf[3]*sc3;
        const float4 v0 = accbuf[0][tid];
        const float4 v1 = accbuf[1][tid];
        const float4 v2 = accbuf[2][tid];
        const float4 v3 = accbuf[3][tid];
        const float r = 1.f / dtot;
        float4 oo;
        oo.x = (v0.x*sc0 + v1.x*sc1 + v2.x*sc2 + v3.x*sc3) * r;
        oo.y = (v0.y*sc0 + v1.y*sc1 + v2.y*sc2 + v3.y*sc3) * r;
        oo.z = (v0.z*sc0 + v1.z*sc1 + v2.z*sc2 + v3.z*sc3) * r;
        oo.w = (v0.w*sc0 + v1.w*sc1 + v2.w*sc2 + v3.w*sc3) * r;
        *(float4*)(out + (size_t)wg * C + tid * 4) = oo;
    }
}

// ---------------------------------------------------------------------------
extern "C" void kernel_launch(void* const* d_in, const int* in_sizes, int n_in,
                              void* d_out, int out_size, void* d_ws, size_t ws_size,
                              hipStream_t stream) {
    const float* q  = (const float*)d_in[0];
    const float* ct = (const float*)d_in[1];
    const float* Wa = (const float*)d_in[2];
    const float* Wp = (const float*)d_in[3];
    const float* Vp = (const float*)d_in[4];
    float* out = (float*)d_out;

    char* ws = (char*)d_ws;
    float* Bp     = (float*)ws;                   // 512 KB
    float* ptpart = (float*)(ws + 524288);        // 128 KB
    float* pt     = (float*)(ws + 655360);        // 32 KB
    int*   cnt    = (int*)  (ws + 688128);        // 1 KB
    int*   offs   = (int*)  (ws + 689152);        // 1 KB
    int*   perm   = (int*)  (ws + 690176);        // 32 KB
    float* g      = (float*)(ws + 722944);        // 8 MB

    prep_B<<<256, 256, 0, stream>>>(Wp, Wa, Bp, cnt);
    precomp_gemm<<<1024, 256, 0, stream>>>(ct, Bp, Vp, ptpart, g);
    pt_hist<<<TOTW / 256, 256, 0, stream>>>(ptpart, pt, cnt);
    scan_kernel<<<1, TBKT, 0, stream>>>(cnt, offs);
    scatter_kernel<<<TOTW / 256, 256, 0, stream>>>(pt, offs, perm);
    attn<<<TOTW, 256, 0, stream>>>(q, g, pt, perm, out);
}